// Round 1
// baseline (249.576 us; speedup 1.0000x reference)
//
#include <hip/hip_runtime.h>

#define DIN 2048
#define WPR 64            // u32 words per row (2048 bits)
#define QPR 32            // u64 words per row
#define BM 128
#define BN 64
#define LDQ 34            // padded u64 stride in LDS (272 B -> conflict-free)
#define LN_EPS 1e-5f

typedef unsigned long long u64;

__device__ inline float wave_sum(float v) {
    #pragma unroll
    for (int off = 32; off; off >>= 1) v += __shfl_down(v, off, 64);
    return v;
}

// ---------------- weight pack: bit = sign(w - rowmean) < 0 ----------------
__global__ __launch_bounds__(256) void w_pack_kernel(const float* __restrict__ w,
                                                     unsigned* __restrict__ wpk) {
    const int row = blockIdx.x;
    const int t = threadIdx.x;
    const float* wr = w + (size_t)row * DIN;
    float4 v0 = ((const float4*)wr)[t * 2];
    float4 v1 = ((const float4*)wr)[t * 2 + 1];
    float s = v0.x + v0.y + v0.z + v0.w + v1.x + v1.y + v1.z + v1.w;

    __shared__ float red[4];
    float wsum = wave_sum(s);
    int wid = t >> 6, lane = t & 63;
    if (lane == 0) red[wid] = wsum;
    __syncthreads();
    float mu = (red[0] + red[1] + red[2] + red[3]) * (1.f / DIN);

    float vv[8] = {v0.x, v0.y, v0.z, v0.w, v1.x, v1.y, v1.z, v1.w};
    unsigned byte = 0;
    #pragma unroll
    for (int j = 0; j < 8; ++j)
        byte |= ((vv[j] - mu) < 0.f ? 1u : 0u) << j;

    __shared__ unsigned char bytes[256];
    bytes[t] = (unsigned char)byte;
    __syncthreads();
    if (t < 64) {
        unsigned wd = (unsigned)bytes[t * 4] | ((unsigned)bytes[t * 4 + 1] << 8) |
                      ((unsigned)bytes[t * 4 + 2] << 16) | ((unsigned)bytes[t * 4 + 3] << 24);
        wpk[(size_t)row * WPR + t] = wd;
    }
}

// ---------------- LN + activation pack: bit = (xn < 0) ----------------
__global__ __launch_bounds__(256) void ln_pack_kernel(const float* __restrict__ x,
                                                      const float* __restrict__ gamma,
                                                      const float* __restrict__ beta,
                                                      unsigned* __restrict__ apk) {
    const int row = blockIdx.x;
    const int t = threadIdx.x;
    const float* xr = x + (size_t)row * DIN;
    float4 v0 = ((const float4*)xr)[t * 2];
    float4 v1 = ((const float4*)xr)[t * 2 + 1];
    float s  = v0.x + v0.y + v0.z + v0.w + v1.x + v1.y + v1.z + v1.w;
    float ss = v0.x * v0.x + v0.y * v0.y + v0.z * v0.z + v0.w * v0.w +
               v1.x * v1.x + v1.y * v1.y + v1.z * v1.z + v1.w * v1.w;

    __shared__ float red[8];
    float wsum = wave_sum(s), wssum = wave_sum(ss);
    int wid = t >> 6, lane = t & 63;
    if (lane == 0) { red[wid] = wsum; red[4 + wid] = wssum; }
    __syncthreads();
    float tot  = red[0] + red[1] + red[2] + red[3];
    float tots = red[4] + red[5] + red[6] + red[7];
    float mu  = tot * (1.f / DIN);
    float var = tots * (1.f / DIN) - mu * mu;
    float rs  = rsqrtf(var + LN_EPS);

    float4 g0 = ((const float4*)gamma)[t * 2];
    float4 g1 = ((const float4*)gamma)[t * 2 + 1];
    float4 b0 = ((const float4*)beta)[t * 2];
    float4 b1 = ((const float4*)beta)[t * 2 + 1];
    float vv[8] = {v0.x, v0.y, v0.z, v0.w, v1.x, v1.y, v1.z, v1.w};
    float gg[8] = {g0.x, g0.y, g0.z, g0.w, g1.x, g1.y, g1.z, g1.w};
    float bb[8] = {b0.x, b0.y, b0.z, b0.w, b1.x, b1.y, b1.z, b1.w};
    unsigned byte = 0;
    #pragma unroll
    for (int j = 0; j < 8; ++j) {
        float xn = (vv[j] - mu) * rs * gg[j] + bb[j];
        byte |= (xn < 0.f ? 1u : 0u) << j;
    }

    __shared__ unsigned char bytes[256];
    bytes[t] = (unsigned char)byte;
    __syncthreads();
    if (t < 64) {
        unsigned wd = (unsigned)bytes[t * 4] | ((unsigned)bytes[t * 4 + 1] << 8) |
                      ((unsigned)bytes[t * 4 + 2] << 16) | ((unsigned)bytes[t * 4 + 3] << 24);
        apk[(size_t)row * WPR + t] = wd;
    }
}

// ---------------- binary GEMM via xor+popcount ----------------
// grid: (N/BN, M/BM), block: 256. Whole K (32 u64) staged once in LDS.
__global__ __launch_bounds__(256) void bingemm_kernel(const u64* __restrict__ A,
                                                      const u64* __restrict__ B,
                                                      const float* __restrict__ bias,
                                                      const float* __restrict__ alpha,
                                                      float* __restrict__ out) {
    __shared__ u64 As[BM * LDQ];   // 34816 B
    __shared__ u64 Bs[BN * LDQ];   // 17408 B
    const int t = threadIdx.x;
    const int bn = blockIdx.x, bm = blockIdx.y;

    // stage A: 128 rows x 16 x 16B chunks = 2048 chunks, 8 per thread
    const uint4* Ag = (const uint4*)(A + (size_t)bm * BM * QPR);
    #pragma unroll
    for (int i = 0; i < 8; ++i) {
        int id = t + i * 256;
        int r = id >> 4, c = id & 15;
        *((uint4*)&As[r * LDQ + c * 2]) = Ag[r * 16 + c];
    }
    // stage B: 64 rows x 16 chunks = 1024 chunks, 4 per thread
    const uint4* Bg = (const uint4*)(B + (size_t)bn * BN * QPR);
    #pragma unroll
    for (int i = 0; i < 4; ++i) {
        int id = t + i * 256;
        int r = id >> 4, c = id & 15;
        *((uint4*)&Bs[r * LDQ + c * 2]) = Bg[r * 16 + c];
    }
    __syncthreads();

    const int tr = t >> 3;        // 0..31 -> 4 rows each
    const int tc = t & 7;         // 0..7  -> 8 cols each
    const u64* Ap = &As[(tr * 4) * LDQ];
    const u64* Bp = &Bs[(tc * 8) * LDQ];

    int acc[4][8] = {};
    #pragma unroll
    for (int k = 0; k < 16; ++k) {
        u64 a[4][2], b[8][2];
        #pragma unroll
        for (int r = 0; r < 4; ++r) {
            a[r][0] = Ap[r * LDQ + k * 2];
            a[r][1] = Ap[r * LDQ + k * 2 + 1];
        }
        #pragma unroll
        for (int c = 0; c < 8; ++c) {
            b[c][0] = Bp[c * LDQ + k * 2];
            b[c][1] = Bp[c * LDQ + k * 2 + 1];
        }
        #pragma unroll
        for (int r = 0; r < 4; ++r)
            #pragma unroll
            for (int c = 0; c < 8; ++c)
                acc[r][c] += __popcll(a[r][0] ^ b[c][0]) + __popcll(a[r][1] ^ b[c][1]);
    }

    // epilogue: dot = 2048 - 2*acc; out = (dot + bias)*alpha
    const int col0 = bn * BN + tc * 8;
    float4 bi0 = ((const float4*)(bias + col0))[0];
    float4 bi1 = ((const float4*)(bias + col0))[1];
    float4 al0 = ((const float4*)(alpha + col0))[0];
    float4 al1 = ((const float4*)(alpha + col0))[1];
    #pragma unroll
    for (int r = 0; r < 4; ++r) {
        const size_t row = (size_t)bm * BM + tr * 4 + r;
        float4 o0, o1;
        o0.x = ((float)(DIN - 2 * acc[r][0]) + bi0.x) * al0.x;
        o0.y = ((float)(DIN - 2 * acc[r][1]) + bi0.y) * al0.y;
        o0.z = ((float)(DIN - 2 * acc[r][2]) + bi0.z) * al0.z;
        o0.w = ((float)(DIN - 2 * acc[r][3]) + bi0.w) * al0.w;
        o1.x = ((float)(DIN - 2 * acc[r][4]) + bi1.x) * al1.x;
        o1.y = ((float)(DIN - 2 * acc[r][5]) + bi1.y) * al1.y;
        o1.z = ((float)(DIN - 2 * acc[r][6]) + bi1.z) * al1.z;
        o1.w = ((float)(DIN - 2 * acc[r][7]) + bi1.w) * al1.w;
        float4* op = (float4*)(out + row * 2048 + col0);
        op[0] = o0;
        op[1] = o1;
    }
}

extern "C" void kernel_launch(void* const* d_in, const int* in_sizes, int n_in,
                              void* d_out, int out_size, void* d_ws, size_t ws_size,
                              hipStream_t stream) {
    const float* x     = (const float*)d_in[0];
    const float* gamma = (const float*)d_in[1];
    const float* beta  = (const float*)d_in[2];
    const float* w     = (const float*)d_in[3];
    const float* bias  = (const float*)d_in[4];
    const float* alpha = (const float*)d_in[5];
    float* out = (float*)d_out;

    const int M = in_sizes[0] / DIN;          // 16384
    const int N = in_sizes[3] / DIN;          // 2048 (D_OUT)

    unsigned* apk = (unsigned*)d_ws;                          // M*64 u32 = 4 MB
    unsigned* wpk = (unsigned*)((char*)d_ws + (size_t)M * WPR * 4);  // N*64 u32 = 0.5 MB

    w_pack_kernel<<<N, 256, 0, stream>>>(w, wpk);
    ln_pack_kernel<<<M, 256, 0, stream>>>(x, gamma, beta, apk);

    dim3 grid(N / BN, M / BM);
    bingemm_kernel<<<grid, 256, 0, stream>>>((const u64*)apk, (const u64*)wpk,
                                             bias, alpha, out);
}

// Round 2
// 172.425 us; speedup vs baseline: 1.4474x; 1.4474x over previous
//
#include <hip/hip_runtime.h>

#define DIN 2048
#define WPR 64            // u32 words per row (2048 bits)
#define QPR 32            // u64 words per row
#define BM 128
#define BN 64
#define LDQ 34            // padded u64 stride in LDS (272 B; granule stride 17, odd -> phase-spread)
#define LN_EPS 1e-5f

typedef unsigned long long u64;

__device__ inline float wave_sum(float v) {
    #pragma unroll
    for (int off = 32; off; off >>= 1) v += __shfl_down(v, off, 64);
    return v;
}

// ---------------- weight pack: bit = sign(w - rowmean) < 0 ----------------
__global__ __launch_bounds__(256) void w_pack_kernel(const float* __restrict__ w,
                                                     unsigned* __restrict__ wpk) {
    const int row = blockIdx.x;
    const int t = threadIdx.x;
    const float* wr = w + (size_t)row * DIN;
    float4 v0 = ((const float4*)wr)[t * 2];
    float4 v1 = ((const float4*)wr)[t * 2 + 1];
    float s = v0.x + v0.y + v0.z + v0.w + v1.x + v1.y + v1.z + v1.w;

    __shared__ float red[4];
    float wsum = wave_sum(s);
    int wid = t >> 6, lane = t & 63;
    if (lane == 0) red[wid] = wsum;
    __syncthreads();
    float mu = (red[0] + red[1] + red[2] + red[3]) * (1.f / DIN);

    float vv[8] = {v0.x, v0.y, v0.z, v0.w, v1.x, v1.y, v1.z, v1.w};
    unsigned byte = 0;
    #pragma unroll
    for (int j = 0; j < 8; ++j)
        byte |= ((vv[j] - mu) < 0.f ? 1u : 0u) << j;

    __shared__ unsigned char bytes[256];
    bytes[t] = (unsigned char)byte;
    __syncthreads();
    if (t < 64) {
        unsigned wd = (unsigned)bytes[t * 4] | ((unsigned)bytes[t * 4 + 1] << 8) |
                      ((unsigned)bytes[t * 4 + 2] << 16) | ((unsigned)bytes[t * 4 + 3] << 24);
        wpk[(size_t)row * WPR + t] = wd;
    }
}

// ---------------- LN + activation pack: bit = (xn < 0) ----------------
__global__ __launch_bounds__(256) void ln_pack_kernel(const float* __restrict__ x,
                                                      const float* __restrict__ gamma,
                                                      const float* __restrict__ beta,
                                                      unsigned* __restrict__ apk) {
    const int row = blockIdx.x;
    const int t = threadIdx.x;
    const float* xr = x + (size_t)row * DIN;
    float4 v0 = ((const float4*)xr)[t * 2];
    float4 v1 = ((const float4*)xr)[t * 2 + 1];
    float s  = v0.x + v0.y + v0.z + v0.w + v1.x + v1.y + v1.z + v1.w;
    float ss = v0.x * v0.x + v0.y * v0.y + v0.z * v0.z + v0.w * v0.w +
               v1.x * v1.x + v1.y * v1.y + v1.z * v1.z + v1.w * v1.w;

    __shared__ float red[8];
    float wsum = wave_sum(s), wssum = wave_sum(ss);
    int wid = t >> 6, lane = t & 63;
    if (lane == 0) { red[wid] = wsum; red[4 + wid] = wssum; }
    __syncthreads();
    float tot  = red[0] + red[1] + red[2] + red[3];
    float tots = red[4] + red[5] + red[6] + red[7];
    float mu  = tot * (1.f / DIN);
    float var = tots * (1.f / DIN) - mu * mu;
    float rs  = rsqrtf(var + LN_EPS);

    float4 g0 = ((const float4*)gamma)[t * 2];
    float4 g1 = ((const float4*)gamma)[t * 2 + 1];
    float4 b0 = ((const float4*)beta)[t * 2];
    float4 b1 = ((const float4*)beta)[t * 2 + 1];
    float vv[8] = {v0.x, v0.y, v0.z, v0.w, v1.x, v1.y, v1.z, v1.w};
    float gg[8] = {g0.x, g0.y, g0.z, g0.w, g1.x, g1.y, g1.z, g1.w};
    float bb[8] = {b0.x, b0.y, b0.z, b0.w, b1.x, b1.y, b1.z, b1.w};
    unsigned byte = 0;
    #pragma unroll
    for (int j = 0; j < 8; ++j) {
        float xn = (vv[j] - mu) * rs * gg[j] + bb[j];
        byte |= (xn < 0.f ? 1u : 0u) << j;
    }

    __shared__ unsigned char bytes[256];
    bytes[t] = (unsigned char)byte;
    __syncthreads();
    if (t < 64) {
        unsigned wd = (unsigned)bytes[t * 4] | ((unsigned)bytes[t * 4 + 1] << 8) |
                      ((unsigned)bytes[t * 4 + 2] << 16) | ((unsigned)bytes[t * 4 + 3] << 24);
        apk[(size_t)row * WPR + t] = wd;
    }
}

// ---------------- binary GEMM via xor+popcount ----------------
// grid: (N/BN, M/BM), block: 256. Whole K (32 u64) staged once in LDS.
// Micro-tile is STRIDED: rows = tr + 32*r, cols = tc + 8*c, so the 8
// distinct lane addresses of each ds_read_b128 land on 8 distinct
// bank-phases ((tr+k)%8 / (tc+k)%8) -> conflict-free broadcast reads.
__global__ __launch_bounds__(256) void bingemm_kernel(const u64* __restrict__ A,
                                                      const u64* __restrict__ B,
                                                      const float* __restrict__ bias,
                                                      const float* __restrict__ alpha,
                                                      float* __restrict__ out) {
    __shared__ u64 As[BM * LDQ];   // 34816 B
    __shared__ u64 Bs[BN * LDQ];   // 17408 B
    const int t = threadIdx.x;
    const int bn = blockIdx.x, bm = blockIdx.y;

    // stage A: 128 rows x 16 x 16B granules, 8 per thread
    const uint4* Ag = (const uint4*)(A + (size_t)bm * BM * QPR);
    #pragma unroll
    for (int i = 0; i < 8; ++i) {
        int id = t + i * 256;
        int r = id >> 4, c = id & 15;
        *((uint4*)&As[r * LDQ + c * 2]) = Ag[r * 16 + c];
    }
    // stage B: 64 rows x 16 granules, 4 per thread
    const uint4* Bg = (const uint4*)(B + (size_t)bn * BN * QPR);
    #pragma unroll
    for (int i = 0; i < 4; ++i) {
        int id = t + i * 256;
        int r = id >> 4, c = id & 15;
        *((uint4*)&Bs[r * LDQ + c * 2]) = Bg[r * 16 + c];
    }
    __syncthreads();

    const int tr = t >> 3;        // 0..31 -> rows tr + 32*r
    const int tc = t & 7;         // 0..7  -> cols tc + 8*c
    const u64* Ap = &As[tr * LDQ];
    const u64* Bp = &Bs[tc * LDQ];

    int acc[4][8] = {};
    #pragma unroll
    for (int k = 0; k < 16; ++k) {
        u64 a[4][2], b[8][2];
        #pragma unroll
        for (int r = 0; r < 4; ++r) {
            ulonglong2 v = *((const ulonglong2*)&Ap[r * 32 * LDQ + k * 2]);
            a[r][0] = v.x; a[r][1] = v.y;
        }
        #pragma unroll
        for (int c = 0; c < 8; ++c) {
            ulonglong2 v = *((const ulonglong2*)&Bp[c * 8 * LDQ + k * 2]);
            b[c][0] = v.x; b[c][1] = v.y;
        }
        #pragma unroll
        for (int r = 0; r < 4; ++r)
            #pragma unroll
            for (int c = 0; c < 8; ++c)
                acc[r][c] += __popcll(a[r][0] ^ b[c][0]) + __popcll(a[r][1] ^ b[c][1]);
    }

    // epilogue: dot = 2048 - 2*acc; out = (dot + bias)*alpha
    float bi[8], al[8];
    #pragma unroll
    for (int c = 0; c < 8; ++c) {
        int col = bn * BN + tc + 8 * c;
        bi[c] = bias[col];
        al[c] = alpha[col];
    }
    #pragma unroll
    for (int r = 0; r < 4; ++r) {
        const size_t row = (size_t)bm * BM + tr + 32 * r;
        float* op = out + row * 2048 + bn * BN + tc;
        #pragma unroll
        for (int c = 0; c < 8; ++c)
            op[8 * c] = ((float)(DIN - 2 * acc[r][c]) + bi[c]) * al[c];
    }
}

extern "C" void kernel_launch(void* const* d_in, const int* in_sizes, int n_in,
                              void* d_out, int out_size, void* d_ws, size_t ws_size,
                              hipStream_t stream) {
    const float* x     = (const float*)d_in[0];
    const float* gamma = (const float*)d_in[1];
    const float* beta  = (const float*)d_in[2];
    const float* w     = (const float*)d_in[3];
    const float* bias  = (const float*)d_in[4];
    const float* alpha = (const float*)d_in[5];
    float* out = (float*)d_out;

    const int M = in_sizes[0] / DIN;          // 16384
    const int N = in_sizes[3] / DIN;          // 2048 (D_OUT)

    unsigned* apk = (unsigned*)d_ws;                          // M*64 u32 = 4 MB
    unsigned* wpk = (unsigned*)((char*)d_ws + (size_t)M * WPR * 4);  // N*64 u32 = 0.5 MB

    w_pack_kernel<<<N, 256, 0, stream>>>(w, wpk);
    ln_pack_kernel<<<M, 256, 0, stream>>>(x, gamma, beta, apk);

    dim3 grid(N / BN, M / BM);
    bingemm_kernel<<<grid, 256, 0, stream>>>((const u64*)apk, (const u64*)wpk,
                                             bias, alpha, out);
}